// Round 1
// baseline (319.161 us; speedup 1.0000x reference)
//
#include <hip/hip_runtime.h>

typedef unsigned short u16;
typedef __bf16 bf16_t;
typedef bf16_t bf16x8 __attribute__((ext_vector_type(8)));
typedef float f32x4 __attribute__((ext_vector_type(4)));
typedef u16 u16x8 __attribute__((ext_vector_type(8)));

#define B_ 8
#define S_ 4096
#define H_ 768
#define D_ 64
#define M_ (B_ * S_)

// round-to-nearest-even fp32 -> bf16
__device__ __forceinline__ u16 f2b(float f) {
  unsigned u = __float_as_uint(f);
  u += 0x7fffu + ((u >> 16) & 1u);
  return (u16)(u >> 16);
}

// ---------------------------------------------------------------------------
// Kernel 1: WbT[n][k] (n in [0,192): 0-63=q,64-127=k,128-191=v), bf16, k-major.
// ---------------------------------------------------------------------------
__global__ __launch_bounds__(256) void wconv_k(const float* __restrict__ Wq,
                                               const float* __restrict__ Wk,
                                               const float* __restrict__ Wv,
                                               u16* __restrict__ WbT) {
  int idx = blockIdx.x * 256 + threadIdx.x;  // 0..147455
  int n = idx / 768;
  int k = idx - n * 768;
  const float* W = (n < 64) ? Wq : ((n < 128) ? Wk : Wv);
  int d = n & 63;
  WbT[idx] = f2b(W[k * 64 + d]);
}

// ---------------------------------------------------------------------------
// Kernel 2: QKV projection. Block = 64 rows x 192 cols, 4 waves.
// Wave w owns col-tiles 3w..3w+2 (16 cols each) x 4 row-tiles.
// q is stored pre-scaled by 0.125*log2(e) so attention softmax uses exp2 raw.
// ---------------------------------------------------------------------------
__global__ __launch_bounds__(256) void qkv_k(const float* __restrict__ x,
                                             const u16* __restrict__ WbT,
                                             const float* __restrict__ bq,
                                             const float* __restrict__ bk,
                                             const float* __restrict__ bv,
                                             u16* __restrict__ qb,
                                             u16* __restrict__ kb,
                                             u16* __restrict__ vb) {
  __shared__ __align__(16) u16 xs[64 * 40];    // 64 rows x 32 k (+8 pad)
  __shared__ __align__(16) u16 ws[192 * 40];   // 192 cols x 32 k (+8 pad)
  const int tid = threadIdx.x;
  const int w = tid >> 6;
  const int ln = tid & 15;
  const int qd = (tid >> 4) & 3;
  const int row0 = blockIdx.x * 64;

  const f32x4 z4 = {0.f, 0.f, 0.f, 0.f};
  f32x4 acc[4][3];
#pragma unroll
  for (int rt = 0; rt < 4; ++rt)
#pragma unroll
    for (int ct = 0; ct < 3; ++ct) acc[rt][ct] = z4;

  const int xr = tid >> 2;       // 0..63
  const int xc = (tid & 3) * 8;  // 0,8,16,24

  for (int kt = 0; kt < 24; ++kt) {
    const int k0 = kt * 32;
    // stage x tile (fp32 -> bf16)
    {
      const float* src = x + (row0 + xr) * 768 + k0 + xc;
      float4 f0 = *(const float4*)(src);
      float4 f1 = *(const float4*)(src + 4);
      u16x8 v;
      v[0] = f2b(f0.x); v[1] = f2b(f0.y); v[2] = f2b(f0.z); v[3] = f2b(f0.w);
      v[4] = f2b(f1.x); v[5] = f2b(f1.y); v[6] = f2b(f1.z); v[7] = f2b(f1.w);
      *(u16x8*)&xs[xr * 40 + xc] = v;
    }
    // stage W tile (already bf16, [col][k] layout)
#pragma unroll
    for (int i = 0; i < 3; ++i) {
      int c = i * 256 + tid;            // 0..767 chunk id
      int r = c >> 2, off = (c & 3) * 8;
      *(u16x8*)&ws[r * 40 + off] = *(const u16x8*)(WbT + r * 768 + k0 + off);
    }
    __syncthreads();
    bf16x8 af[4], bf[3];
#pragma unroll
    for (int rt = 0; rt < 4; ++rt)
      af[rt] = *(const bf16x8*)&xs[(rt * 16 + ln) * 40 + qd * 8];
#pragma unroll
    for (int ct = 0; ct < 3; ++ct)
      bf[ct] = *(const bf16x8*)&ws[(w * 48 + ct * 16 + ln) * 40 + qd * 8];
#pragma unroll
    for (int rt = 0; rt < 4; ++rt)
#pragma unroll
      for (int ct = 0; ct < 3; ++ct)
        acc[rt][ct] = __builtin_amdgcn_mfma_f32_16x16x32_bf16(
            af[rt], bf[ct], acc[rt][ct], 0, 0, 0);
    __syncthreads();
  }
  // epilogue: add bias, fold softmax scale into q, store bf16
#pragma unroll
  for (int ct = 0; ct < 3; ++ct) {
    int col = w * 48 + ct * 16 + ln;  // 0..191, wave-uniform matrix id
    int mat = col >> 6;
    int d = col & 63;
    const float* bp = (mat == 0) ? bq : ((mat == 1) ? bk : bv);
    u16* op = (mat == 0) ? qb : ((mat == 1) ? kb : vb);
    float bias = bp[d];
    float scale = (mat == 0) ? 0.18033688011112042f : 1.0f;  // 0.125*log2(e)
#pragma unroll
    for (int rt = 0; rt < 4; ++rt) {
#pragma unroll
      for (int r = 0; r < 4; ++r) {
        int row = row0 + rt * 16 + qd * 4 + r;
        float vv = (acc[rt][ct][r] + bias) * scale;
        op[row * 64 + d] = f2b(vv);
      }
    }
  }
}

// ---------------------------------------------------------------------------
// Kernel 3: causal flash attention. Block = (batch b, 64-row q-tile qi),
// 4 waves x 16 q-rows. BT=64 KV tiles. Online softmax in base-2 domain
// (scale folded into q). P round-trips through per-wave LDS (C->A layout).
// ---------------------------------------------------------------------------
__global__ __launch_bounds__(256) void attn_k(const u16* __restrict__ qb,
                                              const u16* __restrict__ kb,
                                              const u16* __restrict__ vb,
                                              float* __restrict__ out) {
  __shared__ __align__(16) u16 ks[64 * 72];       // [t][d], natural
  __shared__ __align__(16) u16 vs[64 * 72];       // [d][t], transposed
  __shared__ __align__(16) u16 ps[4 * 16 * 72];   // per-wave P staging
  const int tid = threadIdx.x;
  const int w = tid >> 6, ln = tid & 15, qd = (tid >> 4) & 3;
  const int b = blockIdx.x & 7;                 // batch -> XCD locality
  const int qi = 63 - (blockIdx.x >> 3);        // long blocks first
  const int q0 = qi * 64;
  const int q0w = q0 + w * 16;
  const int base = b * S_;

  bf16x8 qf[2];
  {
    const u16* qrow = qb + (base + q0w + ln) * 64;
    qf[0] = *(const bf16x8*)(qrow + qd * 8);
    qf[1] = *(const bf16x8*)(qrow + 32 + qd * 8);
  }
  const f32x4 z4 = {0.f, 0.f, 0.f, 0.f};
  f32x4 o[4] = {z4, z4, z4, z4};
  float m_[4] = {-INFINITY, -INFINITY, -INFINITY, -INFINITY};
  float l_[4] = {0.f, 0.f, 0.f, 0.f};
  u16* psw = ps + w * (16 * 72);

  const int sr = tid >> 3;       // 0..31
  const int sc = (tid & 7) * 8;  // 0..56

  for (int t0 = 0; t0 <= q0; t0 += 64) {
    // stage K natural, V transposed
#pragma unroll
    for (int i = 0; i < 2; ++i) {
      int r = sr + i * 32;
      *(u16x8*)&ks[r * 72 + sc] = *(const u16x8*)(kb + (base + t0 + r) * 64 + sc);
      u16x8 v = *(const u16x8*)(vb + (base + t0 + r) * 64 + sc);
#pragma unroll
      for (int j = 0; j < 8; ++j) vs[(sc + j) * 72 + r] = v[j];
    }
    __syncthreads();

    // S = Q K^T  (already in log2 domain via folded scale)
    f32x4 s[4] = {z4, z4, z4, z4};
#pragma unroll
    for (int kc = 0; kc < 2; ++kc) {
#pragma unroll
      for (int nt = 0; nt < 4; ++nt) {
        bf16x8 bfr = *(const bf16x8*)&ks[(nt * 16 + ln) * 72 + kc * 32 + qd * 8];
        s[nt] = __builtin_amdgcn_mfma_f32_16x16x32_bf16(qf[kc], bfr, s[nt], 0, 0, 0);
      }
    }
    if (t0 == q0) {  // diagonal tile: causal mask
#pragma unroll
      for (int nt = 0; nt < 4; ++nt) {
        int tg = t0 + nt * 16 + ln;
#pragma unroll
        for (int r = 0; r < 4; ++r)
          if (tg > q0w + qd * 4 + r) s[nt][r] = -INFINITY;
      }
    }
    // online softmax (base 2)
    float mn[4], al[4];
#pragma unroll
    for (int r = 0; r < 4; ++r) {
      float rm = fmaxf(fmaxf(s[0][r], s[1][r]), fmaxf(s[2][r], s[3][r]));
      rm = fmaxf(rm, __shfl_xor(rm, 1));
      rm = fmaxf(rm, __shfl_xor(rm, 2));
      rm = fmaxf(rm, __shfl_xor(rm, 4));
      rm = fmaxf(rm, __shfl_xor(rm, 8));
      mn[r] = fmaxf(m_[r], rm);
      al[r] = __builtin_amdgcn_exp2f(m_[r] - mn[r]);
      m_[r] = mn[r];
    }
#pragma unroll
    for (int nt = 0; nt < 4; ++nt) {
#pragma unroll
      for (int r = 0; r < 4; ++r) {
        float p = __builtin_amdgcn_exp2f(s[nt][r] - mn[r]);
        s[nt][r] = p;
        psw[(qd * 4 + r) * 72 + nt * 16 + ln] = f2b(p);
      }
    }
#pragma unroll
    for (int r = 0; r < 4; ++r) {
      float rs = (s[0][r] + s[1][r]) + (s[2][r] + s[3][r]);
      rs += __shfl_xor(rs, 1);
      rs += __shfl_xor(rs, 2);
      rs += __shfl_xor(rs, 4);
      rs += __shfl_xor(rs, 8);
      l_[r] = l_[r] * al[r] + rs;
      o[0][r] *= al[r]; o[1][r] *= al[r]; o[2][r] *= al[r]; o[3][r] *= al[r];
    }
    // O += P V
#pragma unroll
    for (int kc = 0; kc < 2; ++kc) {
      bf16x8 afr = *(const bf16x8*)&psw[ln * 72 + kc * 32 + qd * 8];
#pragma unroll
      for (int nt = 0; nt < 4; ++nt) {
        bf16x8 bfr = *(const bf16x8*)&vs[(nt * 16 + ln) * 72 + kc * 32 + qd * 8];
        o[nt] = __builtin_amdgcn_mfma_f32_16x16x32_bf16(afr, bfr, o[nt], 0, 0, 0);
      }
    }
    __syncthreads();
  }
#pragma unroll
  for (int r = 0; r < 4; ++r) {
    float inv = 1.0f / l_[r];
    int row = base + q0w + qd * 4 + r;
#pragma unroll
    for (int nt = 0; nt < 4; ++nt)
      out[row * 64 + nt * 16 + ln] = o[nt][r] * inv;
  }
}

// ---------------------------------------------------------------------------
extern "C" void kernel_launch(void* const* d_in, const int* in_sizes, int n_in,
                              void* d_out, int out_size, void* d_ws, size_t ws_size,
                              hipStream_t stream) {
  const float* x  = (const float*)d_in[0];
  const float* Wq = (const float*)d_in[1];
  const float* bq = (const float*)d_in[2];
  const float* Wk = (const float*)d_in[3];
  const float* bk = (const float*)d_in[4];
  const float* Wv = (const float*)d_in[5];
  const float* bv = (const float*)d_in[6];
  float* out = (float*)d_out;

  char* wsp = (char*)d_ws;
  u16* WbT = (u16*)wsp;                       // 192*768*2   = 294912 B
  u16* qb  = (u16*)(wsp + 294912);            // 32768*64*2  = 4 MiB
  u16* kb  = qb + (size_t)M_ * 64;
  u16* vb  = kb + (size_t)M_ * 64;

  hipLaunchKernelGGL(wconv_k, dim3(576), dim3(256), 0, stream, Wq, Wk, Wv, WbT);
  hipLaunchKernelGGL(qkv_k, dim3(512), dim3(256), 0, stream,
                     x, WbT, bq, bk, bv, qb, kb, vb);
  hipLaunchKernelGGL(attn_k, dim3(512), dim3(256), 0, stream, qb, kb, vb, out);
}

// Round 2
// 225.753 us; speedup vs baseline: 1.4138x; 1.4138x over previous
//
#include <hip/hip_runtime.h>

typedef unsigned short u16;
typedef __bf16 bf16_t;
typedef bf16_t bf16x8 __attribute__((ext_vector_type(8)));
typedef float f32x4 __attribute__((ext_vector_type(4)));
typedef u16 u16x8 __attribute__((ext_vector_type(8)));

#define B_ 8
#define S_ 4096
#define H_ 768
#define M_ (B_ * S_)

// round-to-nearest-even fp32 -> bf16
__device__ __forceinline__ u16 f2b(float f) {
  unsigned u = __float_as_uint(f);
  u += 0x7fffu + ((u >> 16) & 1u);
  return (u16)(u >> 16);
}

// async global->LDS, 16B per lane; lds base must be wave-uniform
__device__ __forceinline__ void gl_lds16(const void* g, void* l) {
  __builtin_amdgcn_global_load_lds(
      (const __attribute__((address_space(1))) void*)g,
      (__attribute__((address_space(3))) void*)l, 16, 0, 0);
}

// ---------------------------------------------------------------------------
// Kernel 1: WbT[n][k] bf16 (n: 0-63=q,64-127=k,128-191=v). Coalesced reads,
// LDS transpose, coalesced writes. 36 blocks.
// ---------------------------------------------------------------------------
__global__ __launch_bounds__(256) void wconv_k(const float* __restrict__ Wq,
                                               const float* __restrict__ Wk,
                                               const float* __restrict__ Wv,
                                               u16* __restrict__ WbT) {
  __shared__ float wt[64 * 68];
  const int tid = threadIdx.x;
  int mat = blockIdx.x / 12;
  int k0 = (blockIdx.x % 12) * 64;
  const float* W = (mat == 0) ? Wq : ((mat == 1) ? Wk : Wv);
  int r = tid >> 2, c0 = (tid & 3) * 16;
  const float* src = W + (size_t)(k0 + r) * 64 + c0;
#pragma unroll
  for (int j = 0; j < 16; j += 4)
    *(float4*)&wt[r * 68 + c0 + j] = *(const float4*)(src + j);
  __syncthreads();
  int d = tid >> 2;
  u16* dst = WbT + (size_t)(mat * 64 + d) * 768 + k0 + c0;
  u16x8 o0, o1;
#pragma unroll
  for (int j = 0; j < 8; ++j) o0[j] = f2b(wt[(c0 + j) * 68 + d]);
#pragma unroll
  for (int j = 0; j < 8; ++j) o1[j] = f2b(wt[(c0 + 8 + j) * 68 + d]);
  *(u16x8*)dst = o0;
  *(u16x8*)(dst + 8) = o1;
}

// ---------------------------------------------------------------------------
// Kernel 2: QKV projection, double-buffered (reg prefetch), 1 barrier/iter.
// q pre-scaled by 0.125*log2(e). K,Q stored [s][d]; V stored transposed [d][s].
// ---------------------------------------------------------------------------
__global__ __launch_bounds__(256) void qkv_k(const float* __restrict__ x,
                                             const u16* __restrict__ WbT,
                                             const float* __restrict__ bq,
                                             const float* __restrict__ bk,
                                             const float* __restrict__ bv,
                                             u16* __restrict__ qb,
                                             u16* __restrict__ kb,
                                             u16* __restrict__ vbT) {
  __shared__ __align__(16) u16 smem[2 * 2560 + 2 * 7680];  // xs[2], ws[2]
  const int tid = threadIdx.x;
  const int w = tid >> 6, ln = tid & 15, qd = (tid >> 4) & 3;
  const int row0 = blockIdx.x * 64;

  const f32x4 z4 = {0.f, 0.f, 0.f, 0.f};
  f32x4 acc[4][3];
#pragma unroll
  for (int rt = 0; rt < 4; ++rt)
#pragma unroll
    for (int ct = 0; ct < 3; ++ct) acc[rt][ct] = z4;

  const int xr = tid >> 2, xc = (tid & 3) * 8;
  float4 xf0, xf1;
  u16x8 wf[3];

  auto load_t = [&](int kt) {
    const float* sx = x + (size_t)(row0 + xr) * 768 + kt * 32 + xc;
    xf0 = *(const float4*)sx;
    xf1 = *(const float4*)(sx + 4);
#pragma unroll
    for (int i = 0; i < 3; ++i) {
      int c = i * 256 + tid;
      int r = c >> 2, off = (c & 3) * 8;
      wf[i] = *(const u16x8*)(WbT + (size_t)r * 768 + kt * 32 + off);
    }
  };

  load_t(0);
  for (int kt = 0; kt < 24; ++kt) {
    u16* xs = smem + (kt & 1) * 2560;
    u16* wsb = smem + 5120 + (kt & 1) * 7680;
    {
      u16x8 v;
      v[0] = f2b(xf0.x); v[1] = f2b(xf0.y); v[2] = f2b(xf0.z); v[3] = f2b(xf0.w);
      v[4] = f2b(xf1.x); v[5] = f2b(xf1.y); v[6] = f2b(xf1.z); v[7] = f2b(xf1.w);
      *(u16x8*)&xs[xr * 40 + xc] = v;
#pragma unroll
      for (int i = 0; i < 3; ++i) {
        int c = i * 256 + tid;
        int r = c >> 2, off = (c & 3) * 8;
        *(u16x8*)&wsb[r * 40 + off] = wf[i];
      }
    }
    if (kt < 23) load_t(kt + 1);
    __syncthreads();
    bf16x8 af[4], bfr[3];
#pragma unroll
    for (int rt = 0; rt < 4; ++rt)
      af[rt] = *(const bf16x8*)&xs[(rt * 16 + ln) * 40 + qd * 8];
#pragma unroll
    for (int ct = 0; ct < 3; ++ct)
      bfr[ct] = *(const bf16x8*)&wsb[(w * 48 + ct * 16 + ln) * 40 + qd * 8];
#pragma unroll
    for (int rt = 0; rt < 4; ++rt)
#pragma unroll
      for (int ct = 0; ct < 3; ++ct)
        acc[rt][ct] = __builtin_amdgcn_mfma_f32_16x16x32_bf16(
            af[rt], bfr[ct], acc[rt][ct], 0, 0, 0);
    __syncthreads();
  }

  // epilogue: all compute done; q,k direct stores + v transpose via LDS reuse
  u16* vt = smem;  // 64*72 u16, overlaps staging buffers (safe after barrier)
#pragma unroll
  for (int ct = 0; ct < 3; ++ct) {
    int col = w * 48 + ct * 16 + ln;
    int mat = col >> 6, d = col & 63;
    if (mat < 2) {
      const float* bp = (mat == 0) ? bq : bk;
      u16* op = (mat == 0) ? qb : kb;
      float bias = bp[d];
      float scale = (mat == 0) ? 0.18033688011112042f : 1.0f;
#pragma unroll
      for (int rt = 0; rt < 4; ++rt)
#pragma unroll
        for (int r = 0; r < 4; ++r)
          op[(size_t)(row0 + rt * 16 + qd * 4 + r) * 64 + d] =
              f2b((acc[rt][ct][r] + bias) * scale);
    } else {
      float bias = bv[d];
#pragma unroll
      for (int rt = 0; rt < 4; ++rt)
#pragma unroll
        for (int r = 0; r < 4; ++r)
          vt[d * 72 + rt * 16 + qd * 4 + r] = f2b(acc[rt][ct][r] + bias);
    }
  }
  __syncthreads();
  {
    int d = tid >> 2, so = (tid & 3) * 16;
    int b = row0 >> 12, s0 = row0 & 4095;
    u16* dst = vbT + ((size_t)b * 64 + d) * 4096 + s0 + so;
    *(u16x8*)dst = *(const u16x8*)&vt[d * 72 + so];
    *(u16x8*)(dst + 8) = *(const u16x8*)&vt[d * 72 + so + 8];
  }
}

// ---------------------------------------------------------------------------
// Kernel 3: causal flash attention, KV-split. Block = (b, qi, chunk<=32 tiles).
// No running max (exp2 direct, partials combine linearly). Double-buffered
// K/V staging via global_load_lds + XOR swizzle, 1 barrier/iter.
// ---------------------------------------------------------------------------
__global__ __launch_bounds__(256) void attn_k(const u16* __restrict__ qb,
                                              const u16* __restrict__ kb,
                                              const u16* __restrict__ vbT,
                                              float* __restrict__ po0,
                                              float* __restrict__ po1,
                                              float* __restrict__ pl0,
                                              float* __restrict__ pl1) {
  __shared__ __align__(16) u16 ks[2][4096];
  __shared__ __align__(16) u16 vs[2][4096];
  __shared__ __align__(16) u16 ps[4 * 16 * 88];
  const int tid = threadIdx.x;
  const int w = tid >> 6, ln = tid & 15, qd = (tid >> 4) & 3;
  const int id = blockIdx.x;
  int b, qi, tstart, tcount;
  if (id < 256) {            // qi>=32, chunk0 (32 tiles) — longest first
    b = id & 7; qi = 32 + (id >> 3); tstart = 0; tcount = 32;
  } else if (id < 512) {     // qi>=32, chunk1 (qi-31 tiles), descending
    b = id & 7; qi = 63 - ((id - 256) >> 3); tstart = 32; tcount = qi - 31;
  } else {                   // qi<32, single chunk (qi+1 tiles), descending
    b = id & 7; qi = 31 - ((id - 512) >> 3); tstart = 0; tcount = qi + 1;
  }
  const int q0 = qi * 64, q0w = q0 + w * 16;
  const int base = b * S_;
  const u16* kg = kb + (size_t)base * 64;
  const u16* vg = vbT + (size_t)b * 64 * 4096;

  bf16x8 qf[2];
  {
    const u16* qrow = qb + (size_t)(base + q0w + ln) * 64;
    qf[0] = *(const bf16x8*)(qrow + qd * 8);
    qf[1] = *(const bf16x8*)(qrow + 32 + qd * 8);
  }
  const f32x4 z4 = {0.f, 0.f, 0.f, 0.f};
  f32x4 o[4] = {z4, z4, z4, z4};
  float lp[4] = {0.f, 0.f, 0.f, 0.f};
  u16* psw = ps + w * (16 * 88);
  const int lr = (tid & 63) >> 3, csl = tid & 7;

  auto prefetch = [&](int bufi, int tile) {
    const u16* kt_ = kg + (size_t)tile * 4096;
    const u16* vt_ = vg + tile * 64;
#pragma unroll
    for (int i = 0; i < 2; ++i) {
      int r0 = w * 16 + i * 8;
      int r = r0 + lr;
      int c = csl ^ (r & 7);
      gl_lds16(kt_ + r * 64 + c * 8, &ks[bufi][r0 * 64]);
      gl_lds16(vt_ + (size_t)r * 4096 + c * 8, &vs[bufi][r0 * 64]);
    }
  };

  prefetch(0, tstart);
  int buf = 0;
  for (int it = 0; it < tcount; ++it) {
    __syncthreads();  // drains prefetch vmcnt; protects buf reuse
    if (it + 1 < tcount) prefetch(buf ^ 1, tstart + it + 1);
    const int t0a = (tstart + it) * 64;

    f32x4 s[4] = {z4, z4, z4, z4};
#pragma unroll
    for (int kc = 0; kc < 2; ++kc) {
      int cs = (kc * 4 + qd) ^ (ln & 7);
#pragma unroll
      for (int nt = 0; nt < 4; ++nt) {
        bf16x8 bfr = *(const bf16x8*)&ks[buf][(nt * 16 + ln) * 64 + cs * 8];
        s[nt] = __builtin_amdgcn_mfma_f32_16x16x32_bf16(qf[kc], bfr, s[nt], 0, 0, 0);
      }
    }
    if (t0a == q0) {  // diagonal tile: causal mask
#pragma unroll
      for (int nt = 0; nt < 4; ++nt) {
        int tg = t0a + nt * 16 + ln;
#pragma unroll
        for (int r = 0; r < 4; ++r)
          if (tg > q0w + qd * 4 + r) s[nt][r] = -INFINITY;
      }
    }
#pragma unroll
    for (int nt = 0; nt < 4; ++nt)
#pragma unroll
      for (int r = 0; r < 4; ++r) {
        float p = __builtin_amdgcn_exp2f(s[nt][r]);
        lp[r] += p;
        psw[(qd * 4 + r) * 88 + nt * 16 + ln] = f2b(p);
      }
#pragma unroll
    for (int kc = 0; kc < 2; ++kc) {
      bf16x8 afr = *(const bf16x8*)&psw[ln * 88 + kc * 32 + qd * 8];
      int cs = (kc * 4 + qd) ^ (ln & 7);
#pragma unroll
      for (int nt = 0; nt < 4; ++nt) {
        bf16x8 bfr = *(const bf16x8*)&vs[buf][(nt * 16 + ln) * 64 + cs * 8];
        o[nt] = __builtin_amdgcn_mfma_f32_16x16x32_bf16(afr, bfr, o[nt], 0, 0, 0);
      }
    }
    buf ^= 1;
  }

#pragma unroll
  for (int r = 0; r < 4; ++r) {
    float v = lp[r];
    v += __shfl_xor(v, 1); v += __shfl_xor(v, 2);
    v += __shfl_xor(v, 4); v += __shfl_xor(v, 8);
    lp[r] = v;
  }
  float* op = (tstart == 0) ? po0 : po1;
  float* lpt = (tstart == 0) ? pl0 : pl1;
#pragma unroll
  for (int r = 0; r < 4; ++r) {
    int row = base + q0w + qd * 4 + r;
#pragma unroll
    for (int nt = 0; nt < 4; ++nt)
      op[(size_t)row * 64 + nt * 16 + ln] = o[nt][r];
    if (ln == 0) lpt[row] = lp[r];
  }
}

// ---------------------------------------------------------------------------
// Kernel 4: combine partials: out = (o0 [+ o1]) / (l0 [+ l1])
// ---------------------------------------------------------------------------
__global__ __launch_bounds__(256) void comb_k(const float* __restrict__ po0,
                                              const float* __restrict__ po1,
                                              const float* __restrict__ pl0,
                                              const float* __restrict__ pl1,
                                              float* __restrict__ out) {
  int idx = blockIdx.x * 256 + threadIdx.x;  // 524288 threads
  int r = idx >> 4, d0 = (idx & 15) * 4;
  int qi = (r & 4095) >> 6;
  float4 a = *(const float4*)(po0 + (size_t)r * 64 + d0);
  float l = pl0[r];
  if (qi >= 32) {
    float4 c = *(const float4*)(po1 + (size_t)r * 64 + d0);
    a.x += c.x; a.y += c.y; a.z += c.z; a.w += c.w;
    l += pl1[r];
  }
  float inv = 1.0f / l;
  a.x *= inv; a.y *= inv; a.z *= inv; a.w *= inv;
  *(float4*)(out + (size_t)r * 64 + d0) = a;
}

// ---------------------------------------------------------------------------
extern "C" void kernel_launch(void* const* d_in, const int* in_sizes, int n_in,
                              void* d_out, int out_size, void* d_ws, size_t ws_size,
                              hipStream_t stream) {
  const float* x  = (const float*)d_in[0];
  const float* Wq = (const float*)d_in[1];
  const float* bq = (const float*)d_in[2];
  const float* Wk = (const float*)d_in[3];
  const float* bk = (const float*)d_in[4];
  const float* Wv = (const float*)d_in[5];
  const float* bv = (const float*)d_in[6];
  float* out = (float*)d_out;

  char* wsp = (char*)d_ws;
  u16* WbT = (u16*)wsp;                            //  294912 B
  u16* qb  = (u16*)(wsp + 294912);                 // 4 MiB
  u16* kb  = (u16*)(wsp + 4489216);                // 4 MiB
  u16* vbT = (u16*)(wsp + 8683520);                // 4 MiB (transposed [b][d][s])
  float* po0 = (float*)(wsp + 12877824);           // 8 MiB
  float* po1 = (float*)(wsp + 21266432);           // 8 MiB
  float* pl0 = (float*)(wsp + 29655040);           // 128 KiB
  float* pl1 = (float*)(wsp + 29786112);           // 128 KiB

  hipLaunchKernelGGL(wconv_k, dim3(36), dim3(256), 0, stream, Wq, Wk, Wv, WbT);
  hipLaunchKernelGGL(qkv_k, dim3(512), dim3(256), 0, stream,
                     x, WbT, bq, bk, bv, qb, kb, vbT);
  hipLaunchKernelGGL(attn_k, dim3(768), dim3(256), 0, stream,
                     qb, kb, vbT, po0, po1, pl0, pl1);
  hipLaunchKernelGGL(comb_k, dim3(2048), dim3(256), 0, stream,
                     po0, po1, pl0, pl1, out);
}